// Round 1
// baseline (193.683 us; speedup 1.0000x reference)
//
#include <hip/hip_runtime.h>

#define N_TOK 16384
#define DIM   1024
#define PATHS 8
#define CAP   4096
#define TPB   256
#define NBLK  (N_TOK / TPB)   // 64 routing blocks

// ---- workspace layout (bytes) ----
#define OFF_COUNTS 0          //  8 ints  (pad to 256)
#define OFF_BCNT   256        //  64*8 ints = 2048
#define OFF_BOFF   2304       //  64*8 ints = 2048
#define OFF_PATH   4352       //  16384 ints = 65536
#define OFF_GATE   69888      //  16384 floats = 65536
#define OFF_INV    135424     //  8*4096 ints = 131072
#define OFF_GVAL   266496     //  8*4096 floats = 131072
// total ~388 KB

// A1: per-token argmax/max + per-block path histogram
__global__ void k_route(const float* __restrict__ scores,
                        int* __restrict__ path, float* __restrict__ gate,
                        int* __restrict__ blockCnt) {
    __shared__ int cnt[PATHS];
    int tid = threadIdx.x;
    if (tid < PATHS) cnt[tid] = 0;
    __syncthreads();
    int t = blockIdx.x * TPB + tid;
    const float4* s4 = (const float4*)scores;
    float4 s0 = s4[t * 2];
    float4 s1 = s4[t * 2 + 1];
    float best = s0.x; int bp = 0;
    if (s0.y > best) { best = s0.y; bp = 1; }
    if (s0.z > best) { best = s0.z; bp = 2; }
    if (s0.w > best) { best = s0.w; bp = 3; }
    if (s1.x > best) { best = s1.x; bp = 4; }
    if (s1.y > best) { best = s1.y; bp = 5; }
    if (s1.z > best) { best = s1.z; bp = 6; }
    if (s1.w > best) { best = s1.w; bp = 7; }
    path[t] = bp;
    gate[t] = best;
    atomicAdd(&cnt[bp], 1);
    __syncthreads();
    if (tid < PATHS) blockCnt[blockIdx.x * PATHS + tid] = cnt[tid];
}

// A2: exclusive scan of block histograms (tiny: 8 paths x 64 blocks)
__global__ void k_scan(const int* __restrict__ blockCnt,
                       int* __restrict__ blockOff, int* __restrict__ counts) {
    int p = threadIdx.x;
    if (p < PATHS) {
        int run = 0;
        for (int b = 0; b < NBLK; ++b) {
            blockOff[b * PATHS + p] = run;
            run += blockCnt[b * PATHS + p];
        }
        counts[p] = run;
    }
}

// A3: assign slots (token-order rank within path) via wave ballots, build inverse map
__global__ void k_slot(const int* __restrict__ path, const float* __restrict__ gate,
                       const int* __restrict__ blockOff,
                       int* __restrict__ inv, float* __restrict__ gval) {
    __shared__ int wcnt[4 * PATHS];
    __shared__ int woff[4 * PATHS];
    int tid = threadIdx.x;
    int t = blockIdx.x * TPB + tid;
    int p = path[t];
    int lane = tid & 63;
    int wv = tid >> 6;
    unsigned long long lt_mask = (1ULL << lane) - 1ULL;
    int rank = 0;
    #pragma unroll
    for (int q = 0; q < PATHS; ++q) {
        unsigned long long m = __ballot(p == q);
        if (p == q) rank = __popcll(m & lt_mask);
        if (lane == 0) wcnt[wv * PATHS + q] = __popcll(m);
    }
    __syncthreads();
    if (tid < PATHS) {
        int run = 0;
        for (int w = 0; w < 4; ++w) {
            woff[w * PATHS + tid] = run;
            run += wcnt[w * PATHS + tid];
        }
    }
    __syncthreads();
    int slot = blockOff[blockIdx.x * PATHS + p] + woff[wv * PATHS + p] + rank;
    if (slot < CAP) {
        inv[p * CAP + slot] = t;
        gval[p * CAP + slot] = gate[t];
    }
}

// B: dense gather into output. One block per output row (p, s); 256 threads x float4 = 1024 floats.
__global__ void k_gather(const float* __restrict__ x,
                         const int* __restrict__ inv, const float* __restrict__ gval,
                         const int* __restrict__ counts,
                         float* __restrict__ out) {
    int row = blockIdx.x;              // 0 .. PATHS*CAP-1
    int p = row >> 12;                 // CAP = 4096
    int s = row & (CAP - 1);
    int tid = threadIdx.x;
    float4* orow = (float4*)(out + (size_t)row * DIM);
    if (s < counts[p]) {
        int t = inv[row];
        float g = gval[row];
        const float4* xrow = (const float4*)(x + (size_t)t * DIM);
        float4 v = xrow[tid];
        v.x *= g; v.y *= g; v.z *= g; v.w *= g;
        orow[tid] = v;
    } else {
        orow[tid] = make_float4(0.f, 0.f, 0.f, 0.f);
    }
}

extern "C" void kernel_launch(void* const* d_in, const int* in_sizes, int n_in,
                              void* d_out, int out_size, void* d_ws, size_t ws_size,
                              hipStream_t stream) {
    const float* x      = (const float*)d_in[0];
    const float* scores = (const float*)d_in[1];
    float* out = (float*)d_out;
    char* ws = (char*)d_ws;

    int*   counts   = (int*)  (ws + OFF_COUNTS);
    int*   blockCnt = (int*)  (ws + OFF_BCNT);
    int*   blockOff = (int*)  (ws + OFF_BOFF);
    int*   path     = (int*)  (ws + OFF_PATH);
    float* gate     = (float*)(ws + OFF_GATE);
    int*   inv      = (int*)  (ws + OFF_INV);
    float* gval     = (float*)(ws + OFF_GVAL);

    k_route<<<NBLK, TPB, 0, stream>>>(scores, path, gate, blockCnt);
    k_scan<<<1, 64, 0, stream>>>(blockCnt, blockOff, counts);
    k_slot<<<NBLK, TPB, 0, stream>>>(path, gate, blockOff, inv, gval);
    k_gather<<<PATHS * CAP, TPB, 0, stream>>>(x, inv, gval, counts, out);
}

// Round 2
// 190.358 us; speedup vs baseline: 1.0175x; 1.0175x over previous
//
#include <hip/hip_runtime.h>

#define N_TOK 16384
#define DIM   1024
#define PATHS 8
#define CAP   4096
#define TPB   256
#define NBLK  (N_TOK / TPB)   // 64 routing blocks

// ---- workspace layout (bytes) ----
#define OFF_COUNTS 0          //  8 ints  (pad to 256)
#define OFF_BCNT   256        //  64*8 ints = 2048
#define OFF_PATH   2304       //  16384 ints = 65536
#define OFF_GATE   67840      //  16384 floats = 65536
#define OFF_INV    133376     //  8*4096 ints = 131072
#define OFF_GVAL   264448     //  8*4096 floats = 131072
// total ~386 KB

// A1: per-token argmax/max + per-block path histogram
__global__ void k_route(const float* __restrict__ scores,
                        int* __restrict__ path, float* __restrict__ gate,
                        int* __restrict__ blockCnt) {
    __shared__ int cnt[PATHS];
    int tid = threadIdx.x;
    if (tid < PATHS) cnt[tid] = 0;
    __syncthreads();
    int t = blockIdx.x * TPB + tid;
    const float4* s4 = (const float4*)scores;
    float4 s0 = s4[t * 2];
    float4 s1 = s4[t * 2 + 1];
    float best = s0.x; int bp = 0;
    if (s0.y > best) { best = s0.y; bp = 1; }
    if (s0.z > best) { best = s0.z; bp = 2; }
    if (s0.w > best) { best = s0.w; bp = 3; }
    if (s1.x > best) { best = s1.x; bp = 4; }
    if (s1.y > best) { best = s1.y; bp = 5; }
    if (s1.z > best) { best = s1.z; bp = 6; }
    if (s1.w > best) { best = s1.w; bp = 7; }
    path[t] = bp;
    gate[t] = best;
    atomicAdd(&cnt[bp], 1);
    __syncthreads();
    if (tid < PATHS) blockCnt[blockIdx.x * PATHS + tid] = cnt[tid];
}

// A2: slot assignment. Each block redundantly scans the tiny 64x8 histogram
// (2 KB, L2-resident) to get its own per-path exclusive base — no separate
// scan kernel, no serial single-block dispatch. Block 0 also writes counts.
__global__ void k_slot(const int* __restrict__ path, const float* __restrict__ gate,
                       const int* __restrict__ blockCnt,
                       int* __restrict__ counts,
                       int* __restrict__ inv, float* __restrict__ gval) {
    __shared__ int sBase[PATHS];       // exclusive prefix (blocks < us) per path
    __shared__ int wcnt[4 * PATHS];
    __shared__ int woff[4 * PATHS];
    int tid = threadIdx.x;
    if (tid < PATHS) {
        int p = tid;
        int run = 0, mine = 0;
        #pragma unroll
        for (int b = 0; b < NBLK; ++b) {
            if (b == (int)blockIdx.x) mine = run;
            run += blockCnt[b * PATHS + p];
        }
        sBase[p] = mine;
        if (blockIdx.x == 0) counts[p] = run;
    }
    int t = blockIdx.x * TPB + tid;
    int p = path[t];
    int lane = tid & 63;
    int wv = tid >> 6;
    unsigned long long lt_mask = (1ULL << lane) - 1ULL;
    int rank = 0;
    #pragma unroll
    for (int q = 0; q < PATHS; ++q) {
        unsigned long long m = __ballot(p == q);
        if (p == q) rank = __popcll(m & lt_mask);
        if (lane == 0) wcnt[wv * PATHS + q] = __popcll(m);
    }
    __syncthreads();
    if (tid < PATHS) {
        int run = 0;
        for (int w = 0; w < 4; ++w) {
            woff[w * PATHS + tid] = run;
            run += wcnt[w * PATHS + tid];
        }
    }
    __syncthreads();
    int slot = sBase[p] + woff[wv * PATHS + p] + rank;
    if (slot < CAP) {
        inv[p * CAP + slot] = t;
        gval[p * CAP + slot] = gate[t];
    }
}

// B: dense gather into output. One block per output row (p, s); 256 threads x float4.
__global__ void k_gather(const float* __restrict__ x,
                         const int* __restrict__ inv, const float* __restrict__ gval,
                         const int* __restrict__ counts,
                         float* __restrict__ out) {
    int row = blockIdx.x;              // 0 .. PATHS*CAP-1
    int p = row >> 12;                 // CAP = 4096
    int s = row & (CAP - 1);
    int tid = threadIdx.x;
    float4* orow = (float4*)(out + (size_t)row * DIM);
    if (s < counts[p]) {
        int t = inv[row];
        float g = gval[row];
        const float4* xrow = (const float4*)(x + (size_t)t * DIM);
        float4 v = xrow[tid];
        v.x *= g; v.y *= g; v.z *= g; v.w *= g;
        orow[tid] = v;
    } else {
        orow[tid] = make_float4(0.f, 0.f, 0.f, 0.f);
    }
}

extern "C" void kernel_launch(void* const* d_in, const int* in_sizes, int n_in,
                              void* d_out, int out_size, void* d_ws, size_t ws_size,
                              hipStream_t stream) {
    const float* x      = (const float*)d_in[0];
    const float* scores = (const float*)d_in[1];
    float* out = (float*)d_out;
    char* ws = (char*)d_ws;

    int*   counts   = (int*)  (ws + OFF_COUNTS);
    int*   blockCnt = (int*)  (ws + OFF_BCNT);
    int*   path     = (int*)  (ws + OFF_PATH);
    float* gate     = (float*)(ws + OFF_GATE);
    int*   inv      = (int*)  (ws + OFF_INV);
    float* gval     = (float*)(ws + OFF_GVAL);

    k_route<<<NBLK, TPB, 0, stream>>>(scores, path, gate, blockCnt);
    k_slot<<<NBLK, TPB, 0, stream>>>(path, gate, blockCnt, counts, inv, gval);
    k_gather<<<PATHS * CAP, TPB, 0, stream>>>(x, inv, gval, counts, out);
}